// Round 16
// baseline (383.223 us; speedup 1.0000x reference)
//
#include <hip/hip_runtime.h>
#include <hip/hip_bf16.h>

// Problem constants (from reference)
#define S 2048
#define W 96
#define E 100
#define H 100
#define PD 50

typedef float f32x4 __attribute__((ext_vector_type(4)));

__device__ __forceinline__ float fast_rcp(float x) { return __builtin_amdgcn_rcpf(x); }

// One DPP reduction stage: x += dpp_move(x). Builtin form: the compiler's
// hazard recognizer handles DPP wait-states (R14/R15 lesson: raw asm DPP
// needs manual s_nops and ends up slower than this).
template<int CTRL, int RM, bool BND>
__device__ __forceinline__ float dpp_add(float x) {
    int t = __builtin_amdgcn_update_dpp(0, __float_as_int(x), CTRL, RM, 0xf, BND);
    return x + __int_as_float(t);
}

// K1: ragged-prefix mean pool over word embeddings + doc_feat accumulation
__global__ __launch_bounds__(128) void k_sent(const int* __restrict__ x,
                                              const float* __restrict__ word_emb,
                                              float* __restrict__ sent,
                                              float* __restrict__ doc_sum) {
    __shared__ int toks[W];
    __shared__ int s_len;
    const int i = blockIdx.x, t = threadIdx.x;
    if (t == 0) s_len = 0;
    __syncthreads();
    if (t < W) {
        int tok = x[i * W + t];
        toks[t] = tok;
        if (tok > 0) atomicAdd(&s_len, 1);
    }
    __syncthreads();
    const int len = s_len;
    if (t < E) {
        float acc = 0.0f;
        for (int j = 0; j < len; ++j)
            acc += word_emb[toks[j] * E + t];   // coalesced across t
        float val = acc / (float)max(len, 1);
        sent[i * E + t] = val;
        atomicAdd(&doc_sum[t], val * (1.0f / (float)S));
    }
}

// K2: doc = tanh(doc_feat @ fc1_w.T + fc1_b); cvec = Wc + Ws @ doc
__global__ __launch_bounds__(128) void k_doc(const float* __restrict__ doc_sum,
                                             const float* __restrict__ fc1_w,
                                             const float* __restrict__ fc1_b,
                                             const float* __restrict__ Wc,
                                             const float* __restrict__ Ws,
                                             float* __restrict__ cvec) {
    __shared__ float s_df[E];
    __shared__ float s_doc[H];
    const int t = threadIdx.x;
    if (t < E) s_df[t] = doc_sum[t];
    __syncthreads();
    if (t < H) {
        float acc = fc1_b[t];
        for (int k = 0; k < E; ++k) acc += s_df[k] * fc1_w[t * E + k];
        s_doc[t] = tanhf(acc);
    }
    __syncthreads();
    if (t < H) {
        float c = Wc[t];
        for (int j = 0; j < H; ++j) c += Ws[t * H + j] * s_doc[j];
        cvec[t] = c;
    }
}

// K3: per-row padded layout for the scan.
// packed row i = 64 float4 slots; slot m = (L2E*hWr[2m], h[2m], L2E*hWr[2m+1], h[2m+1]),
// zeros for k>=100.  Slot 50 .x (element 200, a DEAD hWr position) carries
// q[i] = -L2E*(h.cvec + pos.Wp + b). The scan keeps lane 50's t0 = 1 (its h
// is 0), so part(lane50) = t0*q injects q into the wave sum for free.
__global__ __launch_bounds__(128) void k_row(const float* __restrict__ sent,
                                             const float* __restrict__ fc2_w,
                                             const float* __restrict__ fc2_b,
                                             const float* __restrict__ Wr,
                                             const float* __restrict__ cvec,
                                             const float* __restrict__ pos_emb,
                                             const float* __restrict__ Wp,
                                             const float* __restrict__ bptr,
                                             float* __restrict__ packed) {
    __shared__ float s_sent[E];
    __shared__ float s_h[H];
    __shared__ float red[128];
    const int i = blockIdx.x, t = threadIdx.x;
    float* row = packed + (size_t)i * 256;
    if (t < E) s_sent[t] = sent[i * E + t];
    __syncthreads();
    float hv = 0.0f;
    if (t < H) {
        float acc = fc2_b[t];
        for (int k = 0; k < E; ++k) acc += s_sent[k] * fc2_w[t * E + k];
        hv = tanhf(acc);
        s_h[t] = hv;
    }
    __syncthreads();
    {
        const int m = t >> 1, o = (t & 1) * 2;
        if (t < H) {
            float acc = 0.0f;
            for (int k = 0; k < H; ++k) acc += s_h[k] * Wr[k * H + t];   // coalesced across t
            row[m * 4 + o]     = 1.44269504f * acc;  // L2E * hWr
            row[m * 4 + o + 1] = hv;                 // h
        } else {
            if (t != 100) row[m * 4 + o] = 0.0f;   // dead w (element 200 reserved for q)
            row[m * 4 + o + 1] = 0.0f;             // dead h
        }
    }
    float p = 0.0f;
    if (t < H) p = hv * cvec[t];
    if (t < PD) p += pos_emb[i * PD + t] * Wp[t];
    red[t] = p;
    __syncthreads();
    for (int m = 64; m > 0; m >>= 1) {
        if (t < m) red[t] += red[t + m];
        __syncthreads();
    }
    if (t == 0) row[200] = -1.44269504f * (red[0] + bptr[0]);  // slot 50 .x
}

// K4: sequential scan, batch-8 double-buffered manual pipeline (R9 macro
// structure), pinned schedule. P/E split-step with deferred normalization:
//   State = fractions (N,D), t = N/D.
//   P: part = (N0*w0*D1 + N1*w1*D0) * rcp(D0*D1)   [rcp off the normalize path]
//      off-chain: t = N*rcp(D); precomps tph=t+h, c=1+t*h, h3=h^3/3, th3=t*h3
//   E: 5-stage DPP tree (shr1,2,4,8 + bcast15) -> lane31 = sum(0..31),
//      lane63 = sum(32..63); dual readlane; e2 = exp2(s01)*exp2(s23);
//      av = e2+1; a2 = av^2; N' = fmaf(a2, fmaf(t,e2,tph), -h3);
//      D' = fmaf(a2, e2+c, -th3).   (Same tanh-addition algebra as R13.)
// N,D magnitude <= a^3 <= 2^30 (|total| <~ 10), D0*D1 <= 2^60: no overflow.
__global__ __launch_bounds__(64, 1) void k_scan(const f32x4* __restrict__ packed,
                                                float* __restrict__ out) {
    const int l = threadIdx.x;
    const f32x4* pf = packed + l;

    float N0 = (l == 50) ? 1.0f : 0.0f, D0 = 1.0f;   // t0 = N0/D0; lane50 = q carrier
    float N1 = 0.0f, D1 = 1.0f;
    float probbuf = 1.0f;

    f32x4 x0, x1, x2, x3, x4, x5, x6, x7;
    f32x4 y0, y1, y2, y3, y4, y5, y6, y7;

#define SB() __builtin_amdgcn_sched_barrier(0)
#define ISSUE(AR, PTR) \
    asm volatile("global_load_dwordx4 %0, %1, off" : "=v"(AR) : "v"(PTR))
#define ISSUE8(P0, P1, P2, P3, P4, P5, P6, P7)                                \
    SB();                                                                     \
    ISSUE(P0, pf + 0 * 64); ISSUE(P1, pf + 1 * 64);                           \
    ISSUE(P2, pf + 2 * 64); ISSUE(P3, pf + 3 * 64);                           \
    ISSUE(P4, pf + 4 * 64); ISSUE(P5, pf + 5 * 64);                           \
    ISSUE(P6, pf + 6 * 64); ISSUE(P7, pf + 7 * 64);                           \
    pf += 8 * 64;                                                             \
    SB();
#define WAIT_ALL()                                                            \
    SB();                                                                     \
    asm volatile("s_waitcnt vmcnt(0)" ::: "memory");                          \
    SB();

#define STEP(CA_, IDX, G)                                                     \
    {                                                                         \
        const float w0 = CA_.x, h0 = CA_.y, w1 = CA_.z, h1 = CA_.w;           \
        /* P: part from fractions + this row's w (rcp off the norm path) */   \
        float m0  = N0 * w0, m1 = N1 * w1;                                    \
        float D01 = D0 * D1;                                                  \
        float crs = m0 * D1;                                                  \
        float num = fmaf(m1, D0, crs);                                        \
        float part = num * fast_rcp(D01);                                     \
        /* off-chain: normalize t; precomps with this row's h */              \
        float t0 = N0 * fast_rcp(D0);                                         \
        float t1 = N1 * fast_rcp(D1);                                         \
        float tph0 = t0 + h0, tph1 = t1 + h1;                                 \
        float c0 = fmaf(t0, h0, 1.0f), c1 = fmaf(t1, h1, 1.0f);               \
        float h30 = h0 * h0 * (h0 * 0.33333334f);                             \
        float h31 = h1 * h1 * (h1 * 0.33333334f);                             \
        float th30 = t0 * h30, th31 = t1 * h31;                               \
        /* E: 5-stage reduce, dual readlane, split exp2, new fractions */     \
        part = dpp_add<0x111, 0xf, true >(part);                              \
        part = dpp_add<0x112, 0xf, true >(part);                              \
        part = dpp_add<0x114, 0xf, true >(part);                              \
        part = dpp_add<0x118, 0xf, true >(part);                              \
        part = dpp_add<0x142, 0xa, false>(part);                              \
        float s01 = __int_as_float(                                           \
            __builtin_amdgcn_readlane(__float_as_int(part), 31));             \
        float s23 = __int_as_float(                                           \
            __builtin_amdgcn_readlane(__float_as_int(part), 63));             \
        float e2 = exp2f(s01) * exp2f(s23);                                   \
        float av = e2 + 1.0f;                                                 \
        float a2 = av * av;                                                   \
        float nA0 = fmaf(t0, e2, tph0), dA0 = e2 + c0;                        \
        float nA1 = fmaf(t1, e2, tph1), dA1 = e2 + c1;                        \
        N0 = fmaf(a2, nA0, -h30); D0 = fmaf(a2, dA0, -th30);                  \
        N1 = fmaf(a2, nA1, -h31); D1 = fmaf(a2, dA1, -th31);                  \
        probbuf = (l == ((G + IDX) & 63)) ? av : probbuf;                     \
    }
#define COMPUTE8(P0, P1, P2, P3, P4, P5, P6, P7, G)                           \
    STEP(P0, 0, G) STEP(P1, 1, G) STEP(P2, 2, G) STEP(P3, 3, G)               \
    STEP(P4, 4, G) STEP(P5, 5, G) STEP(P6, 6, G) STEP(P7, 7, G)               \
    if (((G) & 63) == 56) out[((G) & ~63) + l] = fast_rcp(probbuf);

    // Preload batch 0 into X and land it.
    ISSUE8(x0, x1, x2, x3, x4, x5, x6, x7)
    WAIT_ALL()

    for (int base = 0; base < S; base += 16) {
        ISSUE8(y0, y1, y2, y3, y4, y5, y6, y7)            // rows base+8..base+15
        COMPUTE8(x0, x1, x2, x3, x4, x5, x6, x7, base)    // rows base..base+7
        WAIT_ALL()                                        // Y landed (issued ~2000cy ago)
        ISSUE8(x0, x1, x2, x3, x4, x5, x6, x7)            // rows base+16..base+23
        COMPUTE8(y0, y1, y2, y3, y4, y5, y6, y7, base + 8)
        WAIT_ALL()                                        // X landed
    }
#undef COMPUTE8
#undef STEP
#undef WAIT_ALL
#undef ISSUE8
#undef ISSUE
#undef SB
}

extern "C" void kernel_launch(void* const* d_in, const int* in_sizes, int n_in,
                              void* d_out, int out_size, void* d_ws, size_t ws_size,
                              hipStream_t stream) {
    const int*   x        = (const int*)  d_in[0];
    const float* word_emb = (const float*)d_in[1];
    const float* pos_emb  = (const float*)d_in[2];
    const float* fc1_w    = (const float*)d_in[3];
    const float* fc1_b    = (const float*)d_in[4];
    const float* fc2_w    = (const float*)d_in[5];
    const float* fc2_b    = (const float*)d_in[6];
    const float* Wc       = (const float*)d_in[7];
    const float* Ws       = (const float*)d_in[8];
    const float* Wr       = (const float*)d_in[9];
    const float* Wp       = (const float*)d_in[10];
    const float* bptr     = (const float*)d_in[11];
    float* out = (float*)d_out;

    float* wsf      = (float*)d_ws;
    float* doc_sum  = wsf;                 // 128 (zeroed each call)
    float* cvec     = wsf + 128;           // 128
    float* sent     = wsf + 256;           // S*E = 204800
    float* packed   = sent + S * E;        // (S+16)*256 floats, 16B-aligned offset

    hipMemsetAsync(doc_sum, 0, E * sizeof(float), stream);
    hipMemsetAsync(packed + (size_t)S * 256, 0, 16 * 256 * sizeof(float), stream);
    k_sent<<<S, 128, 0, stream>>>(x, word_emb, sent, doc_sum);
    k_doc<<<1, 128, 0, stream>>>(doc_sum, fc1_w, fc1_b, Wc, Ws, cvec);
    k_row<<<S, 128, 0, stream>>>(sent, fc2_w, fc2_b, Wr, cvec, pos_emb, Wp, bptr, packed);
    k_scan<<<1, 64, 0, stream>>>((const f32x4*)packed, out);
}

// Round 17
// 329.533 us; speedup vs baseline: 1.1629x; 1.1629x over previous
//
#include <hip/hip_runtime.h>
#include <hip/hip_bf16.h>

// Problem constants (from reference)
#define S 2048
#define W 96
#define E 100
#define H 100
#define PD 50

typedef float f32x4 __attribute__((ext_vector_type(4)));

__device__ __forceinline__ float fast_rcp(float x) { return __builtin_amdgcn_rcpf(x); }

// One DPP reduction stage: x += dpp_move(x). Builtin form: the compiler's
// hazard recognizer handles DPP wait-states (R14/R15 lesson: raw asm DPP
// needs manual s_nops and ends up slower than this).
template<int CTRL, int RM, bool BND>
__device__ __forceinline__ float dpp_add(float x) {
    int t = __builtin_amdgcn_update_dpp(0, __float_as_int(x), CTRL, RM, 0xf, BND);
    return x + __int_as_float(t);
}

// K1: ragged-prefix mean pool over word embeddings + doc_feat accumulation
__global__ __launch_bounds__(128) void k_sent(const int* __restrict__ x,
                                              const float* __restrict__ word_emb,
                                              float* __restrict__ sent,
                                              float* __restrict__ doc_sum) {
    __shared__ int toks[W];
    __shared__ int s_len;
    const int i = blockIdx.x, t = threadIdx.x;
    if (t == 0) s_len = 0;
    __syncthreads();
    if (t < W) {
        int tok = x[i * W + t];
        toks[t] = tok;
        if (tok > 0) atomicAdd(&s_len, 1);
    }
    __syncthreads();
    const int len = s_len;
    if (t < E) {
        float acc = 0.0f;
        for (int j = 0; j < len; ++j)
            acc += word_emb[toks[j] * E + t];   // coalesced across t
        float val = acc / (float)max(len, 1);
        sent[i * E + t] = val;
        atomicAdd(&doc_sum[t], val * (1.0f / (float)S));
    }
}

// K2: doc = tanh(doc_feat @ fc1_w.T + fc1_b); cvec = Wc + Ws @ doc
__global__ __launch_bounds__(128) void k_doc(const float* __restrict__ doc_sum,
                                             const float* __restrict__ fc1_w,
                                             const float* __restrict__ fc1_b,
                                             const float* __restrict__ Wc,
                                             const float* __restrict__ Ws,
                                             float* __restrict__ cvec) {
    __shared__ float s_df[E];
    __shared__ float s_doc[H];
    const int t = threadIdx.x;
    if (t < E) s_df[t] = doc_sum[t];
    __syncthreads();
    if (t < H) {
        float acc = fc1_b[t];
        for (int k = 0; k < E; ++k) acc += s_df[k] * fc1_w[t * E + k];
        s_doc[t] = tanhf(acc);
    }
    __syncthreads();
    if (t < H) {
        float c = Wc[t];
        for (int j = 0; j < H; ++j) c += Ws[t * H + j] * s_doc[j];
        cvec[t] = c;
    }
}

// K3: per-row padded layout for the scan.
// packed row i = 64 float4 slots; slot m = (L2E*hWr[2m], h[2m], L2E*hWr[2m+1], h[2m+1]),
// zeros for k>=100.  Slot 50 .x (element 200, a DEAD hWr position) carries
// q[i] = -L2E*(h.cvec + pos.Wp + b). The scan keeps lane 50's t0 = 1 (its h
// is 0), so part(lane50) = t0*q injects q into the wave sum for free.
__global__ __launch_bounds__(128) void k_row(const float* __restrict__ sent,
                                             const float* __restrict__ fc2_w,
                                             const float* __restrict__ fc2_b,
                                             const float* __restrict__ Wr,
                                             const float* __restrict__ cvec,
                                             const float* __restrict__ pos_emb,
                                             const float* __restrict__ Wp,
                                             const float* __restrict__ bptr,
                                             float* __restrict__ packed) {
    __shared__ float s_sent[E];
    __shared__ float s_h[H];
    __shared__ float red[128];
    const int i = blockIdx.x, t = threadIdx.x;
    float* row = packed + (size_t)i * 256;
    if (t < E) s_sent[t] = sent[i * E + t];
    __syncthreads();
    float hv = 0.0f;
    if (t < H) {
        float acc = fc2_b[t];
        for (int k = 0; k < E; ++k) acc += s_sent[k] * fc2_w[t * E + k];
        hv = tanhf(acc);
        s_h[t] = hv;
    }
    __syncthreads();
    {
        const int m = t >> 1, o = (t & 1) * 2;
        if (t < H) {
            float acc = 0.0f;
            for (int k = 0; k < H; ++k) acc += s_h[k] * Wr[k * H + t];   // coalesced across t
            row[m * 4 + o]     = 1.44269504f * acc;  // L2E * hWr
            row[m * 4 + o + 1] = hv;                 // h
        } else {
            if (t != 100) row[m * 4 + o] = 0.0f;   // dead w (element 200 reserved for q)
            row[m * 4 + o + 1] = 0.0f;             // dead h
        }
    }
    float p = 0.0f;
    if (t < H) p = hv * cvec[t];
    if (t < PD) p += pos_emb[i * PD + t] * Wp[t];
    red[t] = p;
    __syncthreads();
    for (int m = 64; m > 0; m >>= 1) {
        if (t < m) red[t] += red[t + m];
        __syncthreads();
    }
    if (t == 0) row[200] = -1.44269504f * (red[0] + bptr[0]);  // slot 50 .x
}

// K4: sequential scan, batch-8 double-buffered manual pipeline (R9 macro
// structure = R13's, best measured), pinned schedule. vs R13:
//  - 5-stage DPP tree (shr1,2,4,8 + bcast15) + DUAL readlane: lane31 = sum of
//    lanes 0..31, lane63 = sum of 32..63 (one stage fewer than full bcast31).
//  - split exp2: ea*eb; av = fmaf(ea,eb,1) = e2+1 at depth 1 (no chained +1).
//  - av-form Moebius (same algebra as R13, re-associated):
//      N = a2*fmaf(t,av,h) - h^3/3;  D = a2*fmaf(t,h,av) - t*h^3/3
//    [t*a^3 + h*a^2 - h^3/3 = a^2*(t*(e2+1)+h) - h^3/3, a = e2+1]
//  Off-chain: h^3/3, t*h^3/3, probbuf select.  prob = rcp(av) deferred to
//  the once-per-64-steps output write.
__global__ __launch_bounds__(64, 1) void k_scan(const f32x4* __restrict__ packed,
                                                float* __restrict__ out) {
    const int l = threadIdx.x;
    const f32x4* pf = packed + l;

    float t0 = (l == 50) ? 1.0f : 0.0f;   // t = tanh(s); lane50 carries q
    float t1 = 0.0f, probbuf = 1.0f;

    f32x4 x0, x1, x2, x3, x4, x5, x6, x7;
    f32x4 y0, y1, y2, y3, y4, y5, y6, y7;

#define SB() __builtin_amdgcn_sched_barrier(0)
#define ISSUE(AR, PTR) \
    asm volatile("global_load_dwordx4 %0, %1, off" : "=v"(AR) : "v"(PTR))
#define ISSUE8(P0, P1, P2, P3, P4, P5, P6, P7)                                \
    SB();                                                                     \
    ISSUE(P0, pf + 0 * 64); ISSUE(P1, pf + 1 * 64);                           \
    ISSUE(P2, pf + 2 * 64); ISSUE(P3, pf + 3 * 64);                           \
    ISSUE(P4, pf + 4 * 64); ISSUE(P5, pf + 5 * 64);                           \
    ISSUE(P6, pf + 6 * 64); ISSUE(P7, pf + 7 * 64);                           \
    pf += 8 * 64;                                                             \
    SB();
#define WAIT_ALL()                                                            \
    SB();                                                                     \
    asm volatile("s_waitcnt vmcnt(0)" ::: "memory");                          \
    SB();

#define STEP(CA_, IDX, G)                                                     \
    {                                                                         \
        const float w0 = CA_.x, h0 = CA_.y, w1 = CA_.z, h1 = CA_.w;           \
        /* off-chain precomputes */                                           \
        float h30  = h0 * h0 * (h0 * 0.33333334f);                            \
        float h31  = h1 * h1 * (h1 * 0.33333334f);                            \
        float th30 = t0 * h30, th31 = t1 * h31;                               \
        float part = fmaf(t0, w0, t1 * w1);                                   \
        part = dpp_add<0x111, 0xf, true >(part);  /* row_shr:1  */            \
        part = dpp_add<0x112, 0xf, true >(part);  /* row_shr:2  */            \
        part = dpp_add<0x114, 0xf, true >(part);  /* row_shr:4  */            \
        part = dpp_add<0x118, 0xf, true >(part);  /* row_shr:8  */            \
        part = dpp_add<0x142, 0xa, false>(part);  /* row_bcast:15 */          \
        float s01 = __int_as_float(                                           \
            __builtin_amdgcn_readlane(__float_as_int(part), 31));             \
        float s23 = __int_as_float(                                           \
            __builtin_amdgcn_readlane(__float_as_int(part), 63));             \
        float ea = exp2f(s01), eb = exp2f(s23);   /* overlap ~30cy */         \
        float av = fmaf(ea, eb, 1.0f);            /* = e2 + 1 = a */          \
        float a2 = av * av;                                                   \
        float nA0 = fmaf(t0, av, h0), dA0 = fmaf(t0, h0, av);                 \
        float nA1 = fmaf(t1, av, h1), dA1 = fmaf(t1, h1, av);                 \
        float N0 = fmaf(a2, nA0, -h30), D0 = fmaf(a2, dA0, -th30);            \
        float N1 = fmaf(a2, nA1, -h31), D1 = fmaf(a2, dA1, -th31);            \
        t0 = N0 * fast_rcp(D0);                                               \
        t1 = N1 * fast_rcp(D1);                                               \
        probbuf = (l == ((G + IDX) & 63)) ? av : probbuf;                     \
    }
#define COMPUTE8(P0, P1, P2, P3, P4, P5, P6, P7, G)                           \
    STEP(P0, 0, G) STEP(P1, 1, G) STEP(P2, 2, G) STEP(P3, 3, G)               \
    STEP(P4, 4, G) STEP(P5, 5, G) STEP(P6, 6, G) STEP(P7, 7, G)               \
    if (((G) & 63) == 56) out[((G) & ~63) + l] = fast_rcp(probbuf);

    // Preload batch 0 into X and land it.
    ISSUE8(x0, x1, x2, x3, x4, x5, x6, x7)
    WAIT_ALL()

    for (int base = 0; base < S; base += 16) {
        ISSUE8(y0, y1, y2, y3, y4, y5, y6, y7)            // rows base+8..base+15
        COMPUTE8(x0, x1, x2, x3, x4, x5, x6, x7, base)    // rows base..base+7
        WAIT_ALL()                                        // Y landed (issued ~2000cy ago)
        ISSUE8(x0, x1, x2, x3, x4, x5, x6, x7)            // rows base+16..base+23
        COMPUTE8(y0, y1, y2, y3, y4, y5, y6, y7, base + 8)
        WAIT_ALL()                                        // X landed
    }
#undef COMPUTE8
#undef STEP
#undef WAIT_ALL
#undef ISSUE8
#undef ISSUE
#undef SB
}

extern "C" void kernel_launch(void* const* d_in, const int* in_sizes, int n_in,
                              void* d_out, int out_size, void* d_ws, size_t ws_size,
                              hipStream_t stream) {
    const int*   x        = (const int*)  d_in[0];
    const float* word_emb = (const float*)d_in[1];
    const float* pos_emb  = (const float*)d_in[2];
    const float* fc1_w    = (const float*)d_in[3];
    const float* fc1_b    = (const float*)d_in[4];
    const float* fc2_w    = (const float*)d_in[5];
    const float* fc2_b    = (const float*)d_in[6];
    const float* Wc       = (const float*)d_in[7];
    const float* Ws       = (const float*)d_in[8];
    const float* Wr       = (const float*)d_in[9];
    const float* Wp       = (const float*)d_in[10];
    const float* bptr     = (const float*)d_in[11];
    float* out = (float*)d_out;

    float* wsf      = (float*)d_ws;
    float* doc_sum  = wsf;                 // 128 (zeroed each call)
    float* cvec     = wsf + 128;           // 128
    float* sent     = wsf + 256;           // S*E = 204800
    float* packed   = sent + S * E;        // (S+16)*256 floats, 16B-aligned offset

    hipMemsetAsync(doc_sum, 0, E * sizeof(float), stream);
    hipMemsetAsync(packed + (size_t)S * 256, 0, 16 * 256 * sizeof(float), stream);
    k_sent<<<S, 128, 0, stream>>>(x, word_emb, sent, doc_sum);
    k_doc<<<1, 128, 0, stream>>>(doc_sum, fc1_w, fc1_b, Wc, Ws, cvec);
    k_row<<<S, 128, 0, stream>>>(sent, fc2_w, fc2_b, Wr, cvec, pos_emb, Wp, bptr, packed);
    k_scan<<<1, 64, 0, stream>>>((const f32x4*)packed, out);
}